// Round 4
// baseline (161.150 us; speedup 1.0000x reference)
//
#include <hip/hip_runtime.h>
#include <stdint.h>
#include <stddef.h>

#define Tdim 4096
#define Hdim 2048

typedef short short8 __attribute__((ext_vector_type(8)));
typedef float floatx4 __attribute__((ext_vector_type(4)));

// RNE fp32 -> bf16 bit pattern
__device__ __forceinline__ unsigned short f2bf(float f) {
  uint32_t u = __float_as_uint(f);
  u += 0x7fffu + ((u >> 16) & 1u);
  return (unsigned short)(u >> 16);
}

// async global->LDS, 16B per lane. LDS dest is wave-uniform base + lane*16.
__device__ __forceinline__ void load_lds16(const void* g, void* l) {
  __builtin_amdgcn_global_load_lds(
      (__attribute__((address_space(1))) unsigned int*)(uintptr_t)g,
      (__attribute__((address_space(3))) unsigned int*)l,
      16, 0, 0);
}

__device__ __forceinline__ float tanh_fast(float z) {
  // tanh(z) = 1 - 2/(exp(2z)+1); safe for all z
  float e = __expf(z + z);
  return 1.0f - __fdividef(2.0f, e + 1.0f);
}

// aligned LDS vector read (forces ds_read_b128)
__device__ __forceinline__ short8 lds_read8(const unsigned short* p) {
  return *(const short8*)__builtin_assume_aligned(p, 16);
}

// ---- fused convert: blocks [0,4096) cast x -> bf16; blocks [4096,5120)
// transpose+cast b (HxH fp32, [k][n]) -> bt bf16 (N x K, [n][k]) ----
__global__ __launch_bounds__(256) void cvt_kernel(const float* __restrict__ x,
                                                  const float* __restrict__ b,
                                                  unsigned short* __restrict__ xbf,
                                                  unsigned short* __restrict__ bt) {
  __shared__ unsigned short tile[64 * 65];
  const int t = threadIdx.x;
  if (blockIdx.x < 4096) {
    size_t i = ((size_t)blockIdx.x * 256 + t) * 8;
    float4 f0 = *(const float4*)(x + i);
    float4 f1 = *(const float4*)(x + i + 4);
    union { unsigned short u[8]; uint4 v; } o;
    o.u[0] = f2bf(f0.x); o.u[1] = f2bf(f0.y); o.u[2] = f2bf(f0.z); o.u[3] = f2bf(f0.w);
    o.u[4] = f2bf(f1.x); o.u[5] = f2bf(f1.y); o.u[6] = f2bf(f1.z); o.u[7] = f2bf(f1.w);
    *(uint4*)(xbf + i) = o.v;
    return;
  }
  const int tb = blockIdx.x - 4096;
  const int bj = tb & 31;  // n block
  const int bi = tb >> 5;  // k block
  {
    const int r0 = t >> 4, c4 = (t & 15) * 4;
#pragma unroll
    for (int p = 0; p < 4; ++p) {
      int r = r0 + p * 16;
      float4 v = *(const float4*)(b + (size_t)(bi * 64 + r) * Hdim + bj * 64 + c4);
      tile[r * 65 + c4 + 0] = f2bf(v.x);
      tile[r * 65 + c4 + 1] = f2bf(v.y);
      tile[r * 65 + c4 + 2] = f2bf(v.z);
      tile[r * 65 + c4 + 3] = f2bf(v.w);
    }
  }
  __syncthreads();
  {
    const int n = t >> 2, kq = (t & 3) * 16;
    union { unsigned short u[16]; uint4 v[2]; } o;
#pragma unroll
    for (int q = 0; q < 16; ++q) o.u[q] = tile[(kq + q) * 65 + n];
    uint4* dst = (uint4*)(bt + (size_t)(bj * 64 + n) * Hdim + bi * 64 + kq);
    dst[0] = o.v[0];
    dst[1] = o.v[1];
  }
}

// ---- GEMM (s = x @ b) with fused two-stage windowed scan epilogue ----
// 128x128 tile, BK=64, 4 waves 2x2 of 64x64 (4x4 frags of 16x16x32 bf16 MFMA).
// 8 "warm" rows (t0-8..t0-1) computed so the scan warms up locally
// (|a| <= 0.03125 -> influence of h_{t-8} < 1e-12).
// Epilogue is two-stage through a 72-row LDS buffer so the union stays at
// 37.2 KB -> 4 blocks/CU (round-3's 136-row buffer was 70.7 KB -> 2 blocks/CU,
// which cost 13 us of K-loop occupancy).
__global__ __launch_bounds__(256) void gemm_scan_kernel(const unsigned short* __restrict__ A,
                                                        const unsigned short* __restrict__ Bt,
                                                        const float* __restrict__ a_mat,
                                                        float* __restrict__ out) {
  // alignas(16): without it the union's alignment is 4 and the short8 LDS
  // reads get split into 4x ds_read_b32 with 16-way bank conflicts
  // (round-2 regression: SQ_LDS_BANK_CONFLICT 1.26e7 -> 1.30e8, 55 -> 263 us).
  __shared__ alignas(16) union SM {
    struct {
      unsigned short sA[128 * 64];
      unsigned short sB[128 * 64];
      unsigned short sAw[8 * 64];
    } st;                      // 33.8 KB
    float s_tile[72 * 129];    // 37.2 KB; [row][col], pad 129
  } sm;

  const int tid = threadIdx.x;
  const int bn = blockIdx.x, bm = blockIdx.y;
  const int wave = tid >> 6, lane = tid & 63;
  const int wm = (wave >> 1) * 64, wn = (wave & 1) * 64;
  const int l15 = lane & 15, quad = lane >> 4;

  const unsigned short* aSrc = A + ((size_t)(bm * 128 + (tid >> 3)) * Hdim + (tid & 7) * 8);
  const unsigned short* bSrc = Bt + ((size_t)(bn * 128 + (tid >> 3)) * Hdim + (tid & 7) * 8);
  const int tw0 = (bm > 0) ? bm * 128 - 8 : 0;  // clamp keeps addresses valid; bm==0 warm ignored
  const unsigned short* wSrc = A + ((size_t)(tw0 + (lane >> 3)) * Hdim + (lane & 7) * 8);
  unsigned short* aDst = &sm.st.sA[tid * 8];
  unsigned short* bDst = &sm.st.sB[tid * 8];
  unsigned short* wDst = &sm.st.sAw[lane * 8];

  floatx4 acc[4][4] = {};
  floatx4 accw[4] = {};

  for (int k0 = 0; k0 < Hdim; k0 += 64) {
#pragma unroll
    for (int c = 0; c < 4; ++c)
      load_lds16(aSrc + (size_t)c * 32 * Hdim + k0, aDst + c * 2048);
#pragma unroll
    for (int c = 0; c < 4; ++c)
      load_lds16(bSrc + (size_t)c * 32 * Hdim + k0, bDst + c * 2048);
    if (wave == 3) load_lds16(wSrc + k0, wDst);
    __syncthreads();
#pragma unroll
    for (int kk = 0; kk < 64; kk += 32) {
      short8 av[4], bv[4], aw;
#pragma unroll
      for (int i = 0; i < 4; ++i)
        av[i] = lds_read8(&sm.st.sA[(wm + i * 16 + l15) * 64 + kk + quad * 8]);
#pragma unroll
      for (int j = 0; j < 4; ++j)
        bv[j] = lds_read8(&sm.st.sB[(wn + j * 16 + l15) * 64 + kk + quad * 8]);
      aw = lds_read8(&sm.st.sAw[(l15 & 7) * 64 + kk + quad * 8]);
#pragma unroll
      for (int i = 0; i < 4; ++i)
#pragma unroll
        for (int j = 0; j < 4; ++j)
          acc[i][j] = __builtin_amdgcn_mfma_f32_16x16x32_bf16(av[i], bv[j], acc[i][j], 0, 0, 0);
      if (wave < 2) {
#pragma unroll
        for (int j = 0; j < 4; ++j)
          accw[j] = __builtin_amdgcn_mfma_f32_16x16x32_bf16(aw, bv[j], accw[j], 0, 0, 0);
      }
    }
    __syncthreads();
  }

  // ---- stage 1: waves 0,1 (wm==0) dump warm rows (idx 0..7) + rows 0..63
  // (idx 8..71). C/D layout: col = lane&15, row = quad*4 + r. ----
  if (wave < 2) {
    if (quad < 2) {  // warm rows: valid m = 0..7 only
#pragma unroll
      for (int j = 0; j < 4; ++j)
#pragma unroll
        for (int r = 0; r < 4; ++r)
          sm.s_tile[(quad * 4 + r) * 129 + wn + j * 16 + l15] = accw[j][r];
    }
#pragma unroll
    for (int i = 0; i < 4; ++i)
#pragma unroll
      for (int j = 0; j < 4; ++j)
#pragma unroll
        for (int r = 0; r < 4; ++r)
          sm.s_tile[(8 + i * 16 + quad * 4 + r) * 129 + wn + j * 16 + l15] = acc[i][j][r];
  }
  __syncthreads();

  // ---- scan stage 1: half0 scans rows 0..63; half1 warms from rows 56..63 ----
  const int col = tid & 127;
  const float aj = a_mat[bn * 128 + col];
  float h = 0.0f;
  if (tid < 128) {
    if (bm > 0) {
#pragma unroll
      for (int r = 0; r < 8; ++r)  // warm-up (discarded outputs)
        h = tanh_fast(fmaf(aj, h, sm.s_tile[r * 129 + col]));
    }
    const size_t g = (size_t)(bm * 128) * Hdim + bn * 128 + col;
#pragma unroll 4
    for (int r2 = 0; r2 < 64; ++r2) {
      h = tanh_fast(fmaf(aj, h, sm.s_tile[(8 + r2) * 129 + col]));
      out[g + (size_t)r2 * Hdim] = h;
    }
  } else {
#pragma unroll
    for (int w = 0; w < 8; ++w)  // rows 56..63 live at idx 64..71
      h = tanh_fast(fmaf(aj, h, sm.s_tile[(64 + w) * 129 + col]));
  }
  __syncthreads();

  // ---- stage 2: waves 2,3 (wm==64) dump rows 64..127 at idx 0..63 ----
  if (wave >= 2) {
#pragma unroll
    for (int i = 0; i < 4; ++i)
#pragma unroll
      for (int j = 0; j < 4; ++j)
#pragma unroll
        for (int r = 0; r < 4; ++r)
          sm.s_tile[(i * 16 + quad * 4 + r) * 129 + wn + j * 16 + l15] = acc[i][j][r];
  }
  __syncthreads();

  // ---- scan stage 2: half1 scans rows 64..127 ----
  if (tid >= 128) {
    const size_t g = (size_t)(bm * 128 + 64) * Hdim + bn * 128 + col;
#pragma unroll 4
    for (int r2 = 0; r2 < 64; ++r2) {
      h = tanh_fast(fmaf(aj, h, sm.s_tile[r2 * 129 + col]));
      out[g + (size_t)r2 * Hdim] = h;
    }
  }
}

extern "C" void kernel_launch(void* const* d_in, const int* in_sizes, int n_in,
                              void* d_out, int out_size, void* d_ws, size_t ws_size,
                              hipStream_t stream) {
  const float* x = (const float*)d_in[0];
  const float* a = (const float*)d_in[1];
  const float* b = (const float*)d_in[2];
  float* out = (float*)d_out;

  char* ws = (char*)d_ws;
  unsigned short* xbf = (unsigned short*)ws;               // 16.8 MB
  unsigned short* btb = xbf + (size_t)Tdim * Hdim;         // 8.4 MB

  hipLaunchKernelGGL(cvt_kernel, dim3(4096 + (Hdim / 64) * (Hdim / 64)), dim3(256), 0, stream,
                     x, b, xbf, btb);
  hipLaunchKernelGGL(gemm_scan_kernel, dim3(Hdim / 128, Tdim / 128), dim3(256), 0, stream,
                     xbf, btb, a, out);
}

// Round 5
// 147.463 us; speedup vs baseline: 1.0928x; 1.0928x over previous
//
#include <hip/hip_runtime.h>
#include <stdint.h>
#include <stddef.h>

#define Tdim 4096
#define Hdim 2048

typedef short short8 __attribute__((ext_vector_type(8)));
typedef float floatx4 __attribute__((ext_vector_type(4)));

// RNE fp32 -> bf16 bit pattern
__device__ __forceinline__ unsigned short f2bf(float f) {
  uint32_t u = __float_as_uint(f);
  u += 0x7fffu + ((u >> 16) & 1u);
  return (unsigned short)(u >> 16);
}

// async global->LDS, 16B per lane. LDS dest is wave-uniform base + lane*16.
__device__ __forceinline__ void load_lds16(const void* g, void* l) {
  __builtin_amdgcn_global_load_lds(
      (__attribute__((address_space(1))) unsigned int*)(uintptr_t)g,
      (__attribute__((address_space(3))) unsigned int*)l,
      16, 0, 0);
}

__device__ __forceinline__ float tanh_fast(float z) {
  // tanh(z) = 1 - 2/(exp(2z)+1); safe for all z
  float e = __expf(z + z);
  return 1.0f - __fdividef(2.0f, e + 1.0f);
}

// aligned LDS vector read (forces ds_read_b128)
__device__ __forceinline__ short8 lds_read8(const unsigned short* p) {
  return *(const short8*)__builtin_assume_aligned(p, 16);
}

// ---- fused convert: blocks [0,4096) cast x -> bf16; blocks [4096,5120)
// transpose+cast b (HxH fp32, [k][n]) -> bt bf16 (N x K, [n][k]) ----
__global__ __launch_bounds__(256) void cvt_kernel(const float* __restrict__ x,
                                                  const float* __restrict__ b,
                                                  unsigned short* __restrict__ xbf,
                                                  unsigned short* __restrict__ bt) {
  __shared__ unsigned short tile[64 * 65];
  const int t = threadIdx.x;
  if (blockIdx.x < 4096) {
    size_t i = ((size_t)blockIdx.x * 256 + t) * 8;
    float4 f0 = *(const float4*)(x + i);
    float4 f1 = *(const float4*)(x + i + 4);
    union { unsigned short u[8]; uint4 v; } o;
    o.u[0] = f2bf(f0.x); o.u[1] = f2bf(f0.y); o.u[2] = f2bf(f0.z); o.u[3] = f2bf(f0.w);
    o.u[4] = f2bf(f1.x); o.u[5] = f2bf(f1.y); o.u[6] = f2bf(f1.z); o.u[7] = f2bf(f1.w);
    *(uint4*)(xbf + i) = o.v;
    return;
  }
  const int tb = blockIdx.x - 4096;
  const int bj = tb & 31;  // n block
  const int bi = tb >> 5;  // k block
  {
    const int r0 = t >> 4, c4 = (t & 15) * 4;
#pragma unroll
    for (int p = 0; p < 4; ++p) {
      int r = r0 + p * 16;
      float4 v = *(const float4*)(b + (size_t)(bi * 64 + r) * Hdim + bj * 64 + c4);
      tile[r * 65 + c4 + 0] = f2bf(v.x);
      tile[r * 65 + c4 + 1] = f2bf(v.y);
      tile[r * 65 + c4 + 2] = f2bf(v.z);
      tile[r * 65 + c4 + 3] = f2bf(v.w);
    }
  }
  __syncthreads();
  {
    const int n = t >> 2, kq = (t & 3) * 16;
    union { unsigned short u[16]; uint4 v[2]; } o;
#pragma unroll
    for (int q = 0; q < 16; ++q) o.u[q] = tile[(kq + q) * 65 + n];
    uint4* dst = (uint4*)(bt + (size_t)(bj * 64 + n) * Hdim + bi * 64 + kq);
    dst[0] = o.v[0];
    dst[1] = o.v[1];
  }
}

// ---- GEMM: s(MxN fp32) = A(MxK bf16) * B, B supplied as Bt(NxK bf16) ----
// 128x128 tile, BK=64, 4 waves 2x2 of 64x64 (4x4 frags of 16x16x32 MFMA).
// XOR-swizzled LDS: slot (row, chunk c) holds global chunk (c ^ (row&7)),
// where chunks are 16B (8 bf16). Staging keeps the wave-uniform contiguous
// LDS dest required by global_load_lds (swizzle applied to the GLOBAL source
// column); fragment reads XOR the same term. Spreads the 16 rows a quad
// reads across all 32 banks (2-way aliasing = free) instead of one 4-bank
// group (round-1: SQ_LDS_BANK_CONFLICT 1.26e7 ~ 20 us/CU of stalls).
__global__ __launch_bounds__(256) void gemm_bt_kernel(const unsigned short* __restrict__ A,
                                                      const unsigned short* __restrict__ Bt,
                                                      float* __restrict__ C) {
  __shared__ unsigned short sA[128 * 64];
  __shared__ unsigned short sB[128 * 64];
  const int tid = threadIdx.x;
  const int bn = blockIdx.x, bm = blockIdx.y;
  const int wave = tid >> 6, lane = tid & 63;
  const int wm = (wave >> 1) * 64, wn = (wave & 1) * 64;
  const int l15 = lane & 15, quad = lane >> 4;
  const int l7 = l15 & 7;  // row&7 of every row this lane reads fragments from

  // staging: thread tid fills LDS slot (row=tid>>3, chunk=tid&7); it must
  // fetch global chunk (tid&7) ^ (row&7). Row advances by 32 per c-chunk,
  // 32 == 0 (mod 8), so the XOR term is constant per thread.
  const int swz = ((tid & 7) ^ ((tid >> 3) & 7)) * 8;
  const unsigned short* aSrc = A + ((size_t)(bm * 128 + (tid >> 3)) * Hdim + swz);
  const unsigned short* bSrc = Bt + ((size_t)(bn * 128 + (tid >> 3)) * Hdim + swz);
  unsigned short* aDst = &sA[tid * 8];
  unsigned short* bDst = &sB[tid * 8];

  floatx4 acc[4][4] = {};

  for (int k0 = 0; k0 < Hdim; k0 += 64) {
#pragma unroll
    for (int c = 0; c < 4; ++c)
      load_lds16(aSrc + (size_t)c * 32 * Hdim + k0, aDst + c * 2048);
#pragma unroll
    for (int c = 0; c < 4; ++c)
      load_lds16(bSrc + (size_t)c * 32 * Hdim + k0, bDst + c * 2048);
    __syncthreads();
#pragma unroll
    for (int kk = 0; kk < 64; kk += 32) {
      // fragment chunk index = kk/8 + quad, swizzled by row&7 (= l15&7)
      const int coff = (((kk >> 3) + quad) ^ l7) * 8;
      short8 av[4], bv[4];
#pragma unroll
      for (int i = 0; i < 4; ++i)
        av[i] = lds_read8(&sA[(wm + i * 16 + l15) * 64 + coff]);
#pragma unroll
      for (int j = 0; j < 4; ++j)
        bv[j] = lds_read8(&sB[(wn + j * 16 + l15) * 64 + coff]);
#pragma unroll
      for (int i = 0; i < 4; ++i)
#pragma unroll
        for (int j = 0; j < 4; ++j)
          acc[i][j] = __builtin_amdgcn_mfma_f32_16x16x32_bf16(av[i], bv[j], acc[i][j], 0, 0, 0);
    }
    __syncthreads();
  }

  // C/D layout: col = lane&15, row = quad*4 + r (m89/m91-verified)
  const int row0 = bm * 128 + wm + quad * 4;
  const int col0 = bn * 128 + wn + l15;
#pragma unroll
  for (int i = 0; i < 4; ++i)
#pragma unroll
    for (int j = 0; j < 4; ++j)
#pragma unroll
      for (int r = 0; r < 4; ++r)
        C[(size_t)(row0 + i * 16 + r) * Hdim + (col0 + j * 16)] = acc[i][j][r];
}

// ---- windowed parallel "scan": |a| <= 0.03125 so influence of h_{t-8} < 1e-12 ----
__global__ __launch_bounds__(256) void scan_kernel(const float* __restrict__ s,
                                                   const float* __restrict__ a,
                                                   float* __restrict__ out) {
  const int j = blockIdx.x * 256 + threadIdx.x;  // column
  const int t0 = blockIdx.y * 32;                // output chunk start
  const float aj = a[j];
  float h = 0.0f;
  int ts = t0 - 8;
  if (ts < 0) ts = 0;
  for (int t = ts; t < t0; ++t)  // warm-up window (exact for t0==0)
    h = tanh_fast(fmaf(aj, h, s[(size_t)t * Hdim + j]));
#pragma unroll
  for (int t = t0; t < t0 + 32; ++t) {
    h = tanh_fast(fmaf(aj, h, s[(size_t)t * Hdim + j]));
    out[(size_t)t * Hdim + j] = h;
  }
}

extern "C" void kernel_launch(void* const* d_in, const int* in_sizes, int n_in,
                              void* d_out, int out_size, void* d_ws, size_t ws_size,
                              hipStream_t stream) {
  const float* x = (const float*)d_in[0];
  const float* a = (const float*)d_in[1];
  const float* b = (const float*)d_in[2];
  float* out = (float*)d_out;

  char* ws = (char*)d_ws;
  float* s = (float*)ws;                                                 // 33.5 MB
  unsigned short* xbf = (unsigned short*)(ws + (size_t)Tdim * Hdim * 4); // 16.8 MB
  unsigned short* btb = xbf + (size_t)Tdim * Hdim;                       // 8.4 MB

  hipLaunchKernelGGL(cvt_kernel, dim3(4096 + (Hdim / 64) * (Hdim / 64)), dim3(256), 0, stream,
                     x, b, xbf, btb);
  hipLaunchKernelGGL(gemm_bt_kernel, dim3(Hdim / 128, Tdim / 128), dim3(256), 0, stream,
                     xbf, btb, s);
  hipLaunchKernelGGL(scan_kernel, dim3(Hdim / 256, Tdim / 32), dim3(256), 0, stream,
                     s, a, out);
}